// Round 3
// baseline (620.675 us; speedup 1.0000x reference)
//
#include <hip/hip_runtime.h>

// LogSqrt2Quantizer: out[i] = F[bucket(x[i])], plus out[n] = s_x.
//
// bucket: v = rintf(x*65536)+66 (integer-valued fp32 in [66,65602]);
//   octave = rawexp(v)-133 in [0,10]; +1 if mantissa_field(v) > 3474675
//   (= floor((sqrt(2)-1)*2^23)) -> exact half-octave test for integer v.
// F[idx] = lut[qtab[idx]] * s_x; qtab emulates the reference's fp32
//   y/scale -> round-half-even chain exactly (odd |r| hit exact .5 ties):
//   idx 0..10 -> q = {15,14,12,10,9,8,6,4,3,2,0}, nibble-packed 0x0234689ACEF.
//
// R3: same as R2 but nontemporal builtins take a native ext_vector_type
//     (clang rejects HIP_vector_type structs).

#define QTAB 0x0234689ACEFULL

typedef float vf4 __attribute__((ext_vector_type(4)));

__device__ __forceinline__ unsigned bucket_of(float xx) {
    float v = rintf(xx * 65536.0f) + 66.0f;      // exact: *2^16 is exp shift
    unsigned b = __float_as_uint(v);
    return ((b >> 23) - 133u) + ((b & 0x7FFFFFu) > 3474675u);
}

__global__ __launch_bounds__(256) void logq_map_kernel(
    const float* __restrict__ x,
    const float* __restrict__ s_x,
    const float* __restrict__ lut,
    float* __restrict__ out,
    long n)
{
    // Lane-resident remap table: lane L (0..10) holds F[L] = lut[qtab[L]]*s_x.
    const unsigned lane = threadIdx.x & 63u;
    const int q = (int)((QTAB >> (4u * (lane < 11u ? lane : 10u))) & 0xFULL);
    const float Freg = lut[q] * s_x[0];

    const long T  = (long)gridDim.x * (long)blockDim.x;
    const long gi = (long)blockIdx.x * (long)blockDim.x + (long)threadIdx.x;
    const long n4 = n >> 2;
    const vf4* __restrict__ x4 = (const vf4*)x;
    vf4*       __restrict__ o4 = (vf4*)out;

    long i = gi;
    for (; i + T < n4; i += 2 * T) {
        vf4 a = __builtin_nontemporal_load(x4 + i);
        vf4 b = __builtin_nontemporal_load(x4 + i + T);
        vf4 oa, ob;
        oa.x = __shfl(Freg, (int)bucket_of(a.x));
        oa.y = __shfl(Freg, (int)bucket_of(a.y));
        oa.z = __shfl(Freg, (int)bucket_of(a.z));
        oa.w = __shfl(Freg, (int)bucket_of(a.w));
        ob.x = __shfl(Freg, (int)bucket_of(b.x));
        ob.y = __shfl(Freg, (int)bucket_of(b.y));
        ob.z = __shfl(Freg, (int)bucket_of(b.z));
        ob.w = __shfl(Freg, (int)bucket_of(b.w));
        __builtin_nontemporal_store(oa, o4 + i);
        __builtin_nontemporal_store(ob, o4 + i + T);
    }
    for (; i < n4; i += T) {
        vf4 a = __builtin_nontemporal_load(x4 + i);
        vf4 oa;
        oa.x = __shfl(Freg, (int)bucket_of(a.x));
        oa.y = __shfl(Freg, (int)bucket_of(a.y));
        oa.z = __shfl(Freg, (int)bucket_of(a.z));
        oa.w = __shfl(Freg, (int)bucket_of(a.w));
        __builtin_nontemporal_store(oa, o4 + i);
    }

    if (gi == 0) {
        // scalar tail (n % 4, normally empty) — no shfl inside divergent code
        for (long j = n4 * 4; j < n; ++j) {
            unsigned idx = bucket_of(x[j]);
            int qt = (int)((QTAB >> (4u * idx)) & 0xFULL);
            out[j] = lut[qt] * s_x[0];
        }
        out[n] = s_x[0];   // second tuple element: s_x passthrough
    }
}

extern "C" void kernel_launch(void* const* d_in, const int* in_sizes, int n_in,
                              void* d_out, int out_size, void* d_ws, size_t ws_size,
                              hipStream_t stream) {
    const float* x   = (const float*)d_in[0];
    const float* s_x = (const float*)d_in[1];
    const float* lut = (const float*)d_in[5];
    float* out = (float*)d_out;
    const long n = in_sizes[0];

    const long n4 = (n + 3) / 4;
    int blocks = (int)((n4 + 2 * 256 - 1) / (2 * 256));   // ~2 float4/thread
    if (blocks < 1) blocks = 1;
    logq_map_kernel<<<blocks, 256, 0, stream>>>(x, s_x, lut, out, n);
}